// Round 4
// baseline (523.880 us; speedup 1.0000x reference)
//
#include <hip/hip_runtime.h>
#include <hip/hip_bf16.h>
#include <stdint.h>

#define B_ 16
#define C_ 256
#define O_ 256
#define H_ 64
#define W_ 64
#define HP 66
#define WP 66
#define HIDDEN 65
#define TEMP 34.0f

#define BM 128
#define BN 128
#define BK 32

typedef __bf16 bf16x8 __attribute__((ext_vector_type(8)));
typedef float floatx4 __attribute__((ext_vector_type(4)));
typedef unsigned int uint;
typedef unsigned short ushort;

__device__ __forceinline__ ushort f2bf(float f) {
    union { float f; uint32_t u; } v; v.f = f;
    uint32_t u = v.u;
    uint32_t r = (u + 0x7FFFu + ((u >> 16) & 1u)) >> 16;
    return (ushort)r;
}

// ---------------------------------------------------------------------------
// Kernel 1: NCHW fp32 -> zero-padded NHWC bf16 transpose, fused pooling.
// ---------------------------------------------------------------------------
#define LTR 132
__global__ __launch_bounds__(256) void pad_pool_kernel(
    const float* __restrict__ x, ushort* __restrict__ xp,
    float* __restrict__ pooled)
{
    int b  = blockIdx.x / HP;
    int hp = blockIdx.x % HP;
    ushort* xpb = xp + ((size_t)(b * HP + hp)) * WP * C_;
    int tid = threadIdx.x;

    if (hp == 0 || hp == HP - 1) {
        uint* p = (uint*)xpb;
        for (int i = tid; i < WP * C_ / 2; i += 256) p[i] = 0;
        return;
    }
    int h = hp - 1;

    __shared__ uint  tr[64 * LTR];
    __shared__ float pr[8 * 256];

    int wq = tid & 15;
    int sw = (wq & 3) << 3;
    const float* xb = x + (((size_t)b * C_) * H_ + h) * W_ + wq * 4;
    #pragma unroll
    for (int i = 0; i < 8; i++) {
        int cp = i * 16 + (tid >> 4);
        const float* p0 = xb + (size_t)(2 * cp) * H_ * W_;
        float4 v0 = *(const float4*)p0;
        float4 v1 = *(const float4*)(p0 + H_ * W_);
        uint r0 = (uint)f2bf(v0.x) | ((uint)f2bf(v1.x) << 16);
        uint r1 = (uint)f2bf(v0.y) | ((uint)f2bf(v1.y) << 16);
        uint r2 = (uint)f2bf(v0.z) | ((uint)f2bf(v1.z) << 16);
        uint r3 = (uint)f2bf(v0.w) | ((uint)f2bf(v1.w) << 16);
        int col = cp ^ sw;
        tr[(wq * 4 + 0) * LTR + col] = r0;
        tr[(wq * 4 + 1) * LTR + col] = r1;
        tr[(wq * 4 + 2) * LTR + col] = r2;
        tr[(wq * 4 + 3) * LTR + col] = r3;
    }

    if (tid < 32) {
        *(uint4*)(xpb + tid * 8) = uint4{0, 0, 0, 0};
    } else if (tid < 64) {
        *(uint4*)(xpb + (size_t)65 * C_ + (tid - 32) * 8) = uint4{0, 0, 0, 0};
    }
    __syncthreads();

    int cg = tid & 31;
    int wg = tid >> 5;
    float acc[8] = {0, 0, 0, 0, 0, 0, 0, 0};
    #pragma unroll
    for (int i = 0; i < 8; i++) {
        int w = i * 8 + wg;
        int s = ((w >> 2) & 3) << 3;
        uint4 d = *(const uint4*)(&tr[w * LTR + ((cg * 4) ^ s)]);
        *(uint4*)(xpb + (size_t)(w + 1) * C_ + cg * 8) = d;
        acc[0] += __uint_as_float(d.x << 16);
        acc[1] += __uint_as_float(d.x & 0xffff0000u);
        acc[2] += __uint_as_float(d.y << 16);
        acc[3] += __uint_as_float(d.y & 0xffff0000u);
        acc[4] += __uint_as_float(d.z << 16);
        acc[5] += __uint_as_float(d.z & 0xffff0000u);
        acc[6] += __uint_as_float(d.w << 16);
        acc[7] += __uint_as_float(d.w & 0xffff0000u);
    }
    #pragma unroll
    for (int k = 0; k < 8; k++) pr[wg * 256 + cg * 8 + k] = acc[k];
    __syncthreads();

    float s = 0.f;
    #pragma unroll
    for (int j = 0; j < 8; j++) s += pr[j * 256 + tid];
    atomicAdd(&pooled[b * C_ + tid], s);
}

// ---------------------------------------------------------------------------
// Kernel 2: fused attention-MLP + weight aggregation. Grid 256 (one per o).
// Each block redundantly computes the tiny attention (266k FMA) from pooled,
// then aggregates its o-row of the kernel bank into bf16 [b][tap][o][c].
// ---------------------------------------------------------------------------
__global__ __launch_bounds__(256) void att_agg_kernel(
    const float* __restrict__ weight, const float* __restrict__ pooled,
    const float* __restrict__ w1, const float* __restrict__ w2,
    const float* __restrict__ b2, ushort* __restrict__ aggw)
{
    int o = blockIdx.x;
    int tid = threadIdx.x;
    __shared__ float psh[B_ * C_];
    __shared__ float hsh[B_ * HIDDEN];
    __shared__ float a_sh[64];

    for (int i = tid; i < B_ * C_; i += 256) psh[i] = pooled[i] * (1.0f / (H_ * W_));
    __syncthreads();
    for (int i = tid; i < B_ * HIDDEN; i += 256) {
        int bb = i / HIDDEN, j = i % HIDDEN;
        float s = 0.f;
        for (int c = 0; c < C_; c++) s += psh[bb * C_ + c] * w1[j * C_ + c];
        hsh[i] = fmaxf(s, 0.f);
    }
    __syncthreads();
    if (tid < B_) {
        float lg[4];
        float mx = -1e30f;
        for (int k = 0; k < 4; k++) {
            float s = b2[k];
            for (int j = 0; j < HIDDEN; j++) s += hsh[tid * HIDDEN + j] * w2[k * HIDDEN + j];
            lg[k] = s / TEMP;
            mx = fmaxf(mx, lg[k]);
        }
        float den = 0.f;
        for (int k = 0; k < 4; k++) { lg[k] = expf(lg[k] - mx); den += lg[k]; }
        for (int k = 0; k < 4; k++) a_sh[tid * 4 + k] = lg[k] / den;
    }
    __syncthreads();

    int cp = tid & 127, bh = tid >> 7;
    float wv[4][18];
    #pragma unroll
    for (int k = 0; k < 4; k++) {
        const float* wp_ = weight + (((size_t)k * O_ + o) * C_ + cp * 2) * 9;
        #pragma unroll
        for (int t = 0; t < 18; t++) wv[k][t] = wp_[t];
    }
    uint* dst = (uint*)aggw;
    for (int b = bh * 8; b < bh * 8 + 8; b++) {
        float a0 = a_sh[b * 4 + 0], a1 = a_sh[b * 4 + 1];
        float a2 = a_sh[b * 4 + 2], a3 = a_sh[b * 4 + 3];
        #pragma unroll
        for (int t = 0; t < 9; t++) {
            float s0 = a0 * wv[0][t]     + a1 * wv[1][t]     + a2 * wv[2][t]     + a3 * wv[3][t];
            float s1 = a0 * wv[0][9 + t] + a1 * wv[1][9 + t] + a2 * wv[2][9 + t] + a3 * wv[3][9 + t];
            uint p = (uint)f2bf(s0) | ((uint)f2bf(s1) << 16);
            dst[(((size_t)b * 9 + t) * O_ + o) * (C_ / 2) + cp] = p;
        }
    }
}

// ---------------------------------------------------------------------------
// Kernel 3: conv as 9 shifted GEMMs (ty-grouped, 48 MFMA per barrier-pair).
// Staging: buffer_load -> VGPR -> ds_write_b128 at contiguous tid*16B
// (provably conflict-free), XOR-swizzled chunk layout so fragment
// ds_read_b128 are also conflict-free. Next-iter global loads issued after
// the second barrier -> overlap with the 48 MFMAs (round-1-style pipelining).
// ---------------------------------------------------------------------------
__global__ __launch_bounds__(256, 3) void conv_kernel(
    const ushort* __restrict__ xp,    // [B][66][66][C] bf16
    const ushort* __restrict__ aggw,  // [B][9][O][C]  bf16
    float* __restrict__ out)          // [B][O][4096]  f32
{
    __shared__ union {
        struct {
            ushort A[3][BM * BK];      // 3 taps x [o 128][c 32] (chunk-swizzled)
            ushort Bst[2 * WP * BK];   // [prow 2][wp 66][c 32] (chunk-swizzled)
        } st;
        float scr[4 * 16 * 68];
    } u;

    int bid = blockIdx.x;
    int b  = bid >> 6;
    int r  = bid & 63;
    int mt = r >> 5;
    int nt = r & 31;
    int tid = threadIdx.x;
    int h0 = nt * 2;

    int wave = tid >> 6, lane = tid & 63;
    int wr = (wave >> 1) * 64;
    int wc = (wave & 1) * 64;
    int fm = lane & 15;
    int q  = lane >> 4;

    // --- staging source offsets (swizzle-permuted per-lane columns) ---
    int rowA = tid >> 2;
    int ccA  = (tid & 3) ^ ((tid >> 3) & 3);
    const ushort* gA0 = aggw + ((size_t)(b * 9) * O_ + mt * BM + rowA) * C_ + ccA * 8;

    int v0 = tid, v1 = tid + 256, v2 = tid + 512;   // B chunk units, 528 total
    int rB0 = v0 >> 2, rB1 = v1 >> 2, rB2 = v2 >> 2;
    int pr1 = (rB1 >= 66) ? 1 : 0;
    int boff0 = rB0 * C_                           + (((v0 & 3) ^ ((v0 >> 3) & 3)) * 8);
    int boff1 = (pr1 * WP + (rB1 - pr1 * 66)) * C_ + (((v1 & 3) ^ ((v1 >> 3) & 3)) * 8);
    int boff2 = (WP + (rB2 - 66)) * C_             + (((v2 & 3) ^ ((v2 >> 3) & 3)) * 8);
    const ushort* gB0 = xp + ((size_t)b * HP + h0) * WP * C_;

    // --- fragment LDS offsets (ushort units, swizzled, loop-invariant) ---
    int aOffL[4];
    int aswz = (q ^ ((fm >> 1) & 3)) * 8;
    #pragma unroll
    for (int i = 0; i < 4; i++)
        aOffL[i] = (wr + i * 16 + fm) * BK + aswz;

    int prB = wc >> 6;
    int boffL[3][4];
    #pragma unroll
    for (int tt = 0; tt < 3; tt++)
        #pragma unroll
        for (int j = 0; j < 4; j++) {
            int rr = prB * 66 + j * 16 + fm + tt;
            boffL[tt][j] = rr * BK + ((q ^ ((rr >> 1) & 3)) * 8);
        }

    floatx4 acc[4][4] = {};

    // --- prefetch iter 0 into registers ---
    uint4 aR[6], bRv0, bRv1, bRv2;
    #pragma unroll
    for (int t = 0; t < 3; t++) {
        aR[2 * t]     = *(const uint4*)(gA0 + (size_t)t * O_ * C_);
        aR[2 * t + 1] = *(const uint4*)(gA0 + ((size_t)t * O_ + 64) * C_);
    }
    bRv0 = *(const uint4*)(gB0 + boff0);
    bRv1 = *(const uint4*)(gB0 + boff1);
    if (tid < 16) bRv2 = *(const uint4*)(gB0 + boff2);

    for (int it = 0; it < 24; ++it) {
        __syncthreads();                 // prior iteration's reads complete
        #pragma unroll
        for (int t = 0; t < 3; t++) {
            *(uint4*)(&u.st.A[t][tid * 8]) = aR[2 * t];
            *(uint4*)(&u.st.A[t][(tid + 256) * 8]) = aR[2 * t + 1];
        }
        *(uint4*)(&u.st.Bst[v0 * 8]) = bRv0;
        *(uint4*)(&u.st.Bst[v1 * 8]) = bRv1;
        if (tid < 16) *(uint4*)(&u.st.Bst[v2 * 8]) = bRv2;
        __syncthreads();

        // prefetch next iter (overlaps with the 48 MFMAs below)
        if (it < 23) {
            int nit = it + 1;
            int ty = nit >> 3, c0 = (nit & 7) * BK;
            const ushort* gA = gA0 + (size_t)(ty * 3) * O_ * C_ + c0;
            #pragma unroll
            for (int t = 0; t < 3; t++) {
                aR[2 * t]     = *(const uint4*)(gA + (size_t)t * O_ * C_);
                aR[2 * t + 1] = *(const uint4*)(gA + ((size_t)t * O_ + 64) * C_);
            }
            const ushort* gB = gB0 + (size_t)ty * WP * C_ + c0;
            bRv0 = *(const uint4*)(gB + boff0);
            bRv1 = *(const uint4*)(gB + boff1);
            if (tid < 16) bRv2 = *(const uint4*)(gB + boff2);
        }

        #pragma unroll
        for (int tt = 0; tt < 3; tt++) {
            bf16x8 af[4], bv[4];
            #pragma unroll
            for (int i = 0; i < 4; i++) af[i] = *(const bf16x8*)(&u.st.A[tt][aOffL[i]]);
            #pragma unroll
            for (int j = 0; j < 4; j++) bv[j] = *(const bf16x8*)(&u.st.Bst[boffL[tt][j]]);
            #pragma unroll
            for (int i = 0; i < 4; i++)
                #pragma unroll
                for (int j = 0; j < 4; j++)
                    acc[i][j] = __builtin_amdgcn_mfma_f32_16x16x32_bf16(af[i], bv[j], acc[i][j], 0, 0, 0);
        }
    }

    // --- epilogue: per-wave LDS transpose -> float4 stores ---
    __syncthreads();
    float* outb = out + ((size_t)b * O_ + mt * BM) * (H_ * W_) + (size_t)nt * BN;
    float* myscr = u.scr + wave * (16 * 68);
    int mrow = lane >> 4;
    int n4 = lane & 15;
    #pragma unroll
    for (int i = 0; i < 4; i++) {
        #pragma unroll
        for (int j = 0; j < 4; j++)
            #pragma unroll
            for (int rr = 0; rr < 4; rr++)
                myscr[(q * 4 + rr) * 68 + j * 16 + fm] = acc[i][j][rr];
        #pragma unroll
        for (int mm = 0; mm < 4; mm++) {
            int m16 = mm * 4 + mrow;
            float4 d = *(const float4*)(&myscr[m16 * 68 + n4 * 4]);
            *(float4*)(&outb[(size_t)(wr + i * 16 + m16) * (H_ * W_) + wc + n4 * 4]) = d;
        }
    }
}

// ---------------------------------------------------------------------------
extern "C" void kernel_launch(void* const* d_in, const int* in_sizes, int n_in,
                              void* d_out, int out_size, void* d_ws, size_t ws_size,
                              hipStream_t stream) {
    const float* x      = (const float*)d_in[0];
    const float* weight = (const float*)d_in[1];
    const float* att_w1 = (const float*)d_in[2];
    const float* att_w2 = (const float*)d_in[3];
    const float* att_b2 = (const float*)d_in[4];
    float* out = (float*)d_out;

    char* ws = (char*)d_ws;
    float* pooled  = (float*)ws;                                  // 16 KiB
    ushort* aggw   = (ushort*)(ws + 32768);                       // 18,874,368 B
    ushort* xp     = (ushort*)(ws + 32768 + 18874368);            // 35,684,352 B

    hipMemsetAsync(pooled, 0, B_ * C_ * sizeof(float), stream);
    pad_pool_kernel<<<B_ * HP, 256, 0, stream>>>(x, xp, pooled);
    att_agg_kernel<<<O_, 256, 0, stream>>>(weight, pooled, att_w1, att_w2, att_b2, aggw);
    conv_kernel<<<B_ * 64, 256, 0, stream>>>(xp, aggw, out);
}

// Round 5
// 241.526 us; speedup vs baseline: 2.1690x; 2.1690x over previous
//
#include <hip/hip_runtime.h>
#include <hip/hip_bf16.h>
#include <stdint.h>

#define B_ 16
#define C_ 256
#define O_ 256
#define H_ 64
#define W_ 64
#define HP 66
#define WP 66
#define HIDDEN 65
#define TEMP 34.0f
#define BK 32
#define LDK 40   // ushort row stride (20 dwords): 8 consecutive rows hit 8 distinct bank-quads

typedef __bf16 bf16x8 __attribute__((ext_vector_type(8)));
typedef float floatx16 __attribute__((ext_vector_type(16)));
typedef unsigned int uint;
typedef unsigned short ushort;

__device__ __forceinline__ ushort f2bf(float f) {
    union { float f; uint32_t u; } v; v.f = f;
    uint32_t u = v.u;
    uint32_t r = (u + 0x7FFFu + ((u >> 16) & 1u)) >> 16;
    return (ushort)r;
}

// ---------------------------------------------------------------------------
// Kernel 1: NCHW fp32 -> zero-padded NHWC bf16 transpose, fused pooling.
// (unchanged from R1 — known 135-µs-era behavior; revisit after conv)
// ---------------------------------------------------------------------------
#define LTR 132
__global__ __launch_bounds__(256) void pad_pool_kernel(
    const float* __restrict__ x, ushort* __restrict__ xp,
    float* __restrict__ pooled)
{
    int b  = blockIdx.x / HP;
    int hp = blockIdx.x % HP;
    ushort* xpb = xp + ((size_t)(b * HP + hp)) * WP * C_;
    int tid = threadIdx.x;

    if (hp == 0 || hp == HP - 1) {
        uint* p = (uint*)xpb;
        for (int i = tid; i < WP * C_ / 2; i += 256) p[i] = 0;
        return;
    }
    int h = hp - 1;

    __shared__ uint  tr[64 * LTR];
    __shared__ float pr[8 * 256];

    int wq = tid & 15;
    int sw = (wq & 3) << 3;
    const float* xb = x + (((size_t)b * C_) * H_ + h) * W_ + wq * 4;
    #pragma unroll
    for (int i = 0; i < 8; i++) {
        int cp = i * 16 + (tid >> 4);
        const float* p0 = xb + (size_t)(2 * cp) * H_ * W_;
        float4 v0 = *(const float4*)p0;
        float4 v1 = *(const float4*)(p0 + H_ * W_);
        uint r0 = (uint)f2bf(v0.x) | ((uint)f2bf(v1.x) << 16);
        uint r1 = (uint)f2bf(v0.y) | ((uint)f2bf(v1.y) << 16);
        uint r2 = (uint)f2bf(v0.z) | ((uint)f2bf(v1.z) << 16);
        uint r3 = (uint)f2bf(v0.w) | ((uint)f2bf(v1.w) << 16);
        int col = cp ^ sw;
        tr[(wq * 4 + 0) * LTR + col] = r0;
        tr[(wq * 4 + 1) * LTR + col] = r1;
        tr[(wq * 4 + 2) * LTR + col] = r2;
        tr[(wq * 4 + 3) * LTR + col] = r3;
    }

    if (tid < 32) {
        *(uint4*)(xpb + tid * 8) = uint4{0, 0, 0, 0};
    } else if (tid < 64) {
        *(uint4*)(xpb + (size_t)65 * C_ + (tid - 32) * 8) = uint4{0, 0, 0, 0};
    }
    __syncthreads();

    int cg = tid & 31;
    int wg = tid >> 5;
    float acc[8] = {0, 0, 0, 0, 0, 0, 0, 0};
    #pragma unroll
    for (int i = 0; i < 8; i++) {
        int w = i * 8 + wg;
        int s = ((w >> 2) & 3) << 3;
        uint4 d = *(const uint4*)(&tr[w * LTR + ((cg * 4) ^ s)]);
        *(uint4*)(xpb + (size_t)(w + 1) * C_ + cg * 8) = d;
        acc[0] += __uint_as_float(d.x << 16);
        acc[1] += __uint_as_float(d.x & 0xffff0000u);
        acc[2] += __uint_as_float(d.y << 16);
        acc[3] += __uint_as_float(d.y & 0xffff0000u);
        acc[4] += __uint_as_float(d.z << 16);
        acc[5] += __uint_as_float(d.z & 0xffff0000u);
        acc[6] += __uint_as_float(d.w << 16);
        acc[7] += __uint_as_float(d.w & 0xffff0000u);
    }
    #pragma unroll
    for (int k = 0; k < 8; k++) pr[wg * 256 + cg * 8 + k] = acc[k];
    __syncthreads();

    float s = 0.f;
    #pragma unroll
    for (int j = 0; j < 8; j++) s += pr[j * 256 + tid];
    atomicAdd(&pooled[b * C_ + tid], s);
}

// ---------------------------------------------------------------------------
// Kernel 2: fused attention-MLP + weight aggregation (R4 version, verified).
// ---------------------------------------------------------------------------
__global__ __launch_bounds__(256) void att_agg_kernel(
    const float* __restrict__ weight, const float* __restrict__ pooled,
    const float* __restrict__ w1, const float* __restrict__ w2,
    const float* __restrict__ b2, ushort* __restrict__ aggw)
{
    int o = blockIdx.x;
    int tid = threadIdx.x;
    __shared__ float psh[B_ * C_];
    __shared__ float hsh[B_ * HIDDEN];
    __shared__ float a_sh[64];

    for (int i = tid; i < B_ * C_; i += 256) psh[i] = pooled[i] * (1.0f / (H_ * W_));
    __syncthreads();
    for (int i = tid; i < B_ * HIDDEN; i += 256) {
        int bb = i / HIDDEN, j = i % HIDDEN;
        float s = 0.f;
        for (int c = 0; c < C_; c++) s += psh[bb * C_ + c] * w1[j * C_ + c];
        hsh[i] = fmaxf(s, 0.f);
    }
    __syncthreads();
    if (tid < B_) {
        float lg[4];
        float mx = -1e30f;
        for (int k = 0; k < 4; k++) {
            float s = b2[k];
            for (int j = 0; j < HIDDEN; j++) s += hsh[tid * HIDDEN + j] * w2[k * HIDDEN + j];
            lg[k] = s / TEMP;
            mx = fmaxf(mx, lg[k]);
        }
        float den = 0.f;
        for (int k = 0; k < 4; k++) { lg[k] = expf(lg[k] - mx); den += lg[k]; }
        for (int k = 0; k < 4; k++) a_sh[tid * 4 + k] = lg[k] / den;
    }
    __syncthreads();

    int cp = tid & 127, bh = tid >> 7;
    float wv[4][18];
    #pragma unroll
    for (int k = 0; k < 4; k++) {
        const float* wp_ = weight + (((size_t)k * O_ + o) * C_ + cp * 2) * 9;
        #pragma unroll
        for (int t = 0; t < 18; t++) wv[k][t] = wp_[t];
    }
    uint* dst = (uint*)aggw;
    for (int b = bh * 8; b < bh * 8 + 8; b++) {
        float a0 = a_sh[b * 4 + 0], a1 = a_sh[b * 4 + 1];
        float a2 = a_sh[b * 4 + 2], a3 = a_sh[b * 4 + 3];
        #pragma unroll
        for (int t = 0; t < 9; t++) {
            float s0 = a0 * wv[0][t]     + a1 * wv[1][t]     + a2 * wv[2][t]     + a3 * wv[3][t];
            float s1 = a0 * wv[0][9 + t] + a1 * wv[1][9 + t] + a2 * wv[2][9 + t] + a3 * wv[3][9 + t];
            uint p = (uint)f2bf(s0) | ((uint)f2bf(s1) << 16);
            dst[(((size_t)b * 9 + t) * O_ + o) * (C_ / 2) + cp] = p;
        }
    }
}

// ---------------------------------------------------------------------------
// Kernel 3: conv via 32x32x16 MFMA. Block tile 128(M=o) x 256(N=4 image rows),
// 4 waves as 2x2 -> wave tile 64x128, acc 2x4 floatx16 = 128 regs.
// ty-grouped: per (ty,c0) window stage A (3 taps x 128 x 32) + B (4 rows x 66
// x 32) once, run 48 MFMAs. Padded LDS rows (LDK=40) => conflict-free frags.
// Grid 512 = 2 blocks/CU; XCD swizzle keeps A-slab sharers on one XCD.
// ---------------------------------------------------------------------------
__global__ __launch_bounds__(256, 2) void conv_kernel(
    const ushort* __restrict__ xp,    // [B][66][66][C] bf16
    const ushort* __restrict__ aggw,  // [B][9][O][C]  bf16
    float* __restrict__ out)          // [B][O][4096]  f32
{
    __shared__ ushort As[3 * 128 * LDK];   // 30720 B
    __shared__ ushort Bs[264 * LDK];       // 21120 B

    // XCD-aware swizzle: bid -> (pair=(b,mt), nt) with all 16 nt of a pair on
    // one XCD (dispatch round-robins bid%8 across 8 XCDs).
    int bid = blockIdx.x;
    int xcd = bid & 7, slot = bid >> 3;          // slot 0..63
    int pair = xcd * 4 + (slot >> 4);            // 0..31
    int nt = slot & 15;
    int b = pair >> 1, mt = pair & 1;

    int tid = threadIdx.x;
    int r0 = nt * 4;                             // first image row of this block

    int wave = tid >> 6, lane = tid & 63;
    int wm = wave >> 1, wn = wave & 1;
    int n31 = lane & 31, h = lane >> 5;

    // --- staging statics ---
    int Ag[6], Al[6];
    #pragma unroll
    for (int s = 0; s < 6; s++) {
        int cid = tid + 256 * s;                 // 0..1535 over [tt 3][row 128][kc 4]
        int kc = cid & 3, row = (cid >> 2) & 127, tt = cid >> 9;
        Ag[s] = (tt * O_ + row) * C_ + kc * 8;
        Al[s] = (tt * 128 + row) * LDK + kc * 8;
    }
    int Bg[5], Bl[5];
    #pragma unroll
    for (int s = 0; s < 5; s++) {
        int cid = tid + 256 * s;                 // 0..1055 over [wr 4][wp 66][kc 4]
        int kc = cid & 3, rw = cid >> 2;
        int wr_ = rw / 66, wp = rw - wr_ * 66;
        Bg[s] = ((r0 + wr_) * WP + wp) * C_ + kc * 8;
        Bl[s] = rw * LDK + kc * 8;
    }
    const ushort* gA0 = aggw + ((size_t)b * 9 * O_ + (size_t)mt * 128) * C_;
    const ushort* gB0 = xp + (size_t)b * HP * WP * C_;

    // --- fragment LDS offsets (ushort units) ---
    int aO[2];
    #pragma unroll
    for (int im = 0; im < 2; im++)
        aO[im] = (wm * 64 + im * 32 + n31) * LDK + h * 8;
    int bO[3][4];
    #pragma unroll
    for (int tx = 0; tx < 3; tx++)
        #pragma unroll
        for (int jn = 0; jn < 4; jn++) {
            int nb = wn * 128 + jn * 32;
            bO[tx][jn] = ((nb >> 6) * 66 + (nb & 63) + tx + n31) * LDK + h * 8;
        }

    floatx16 acc[2][4] = {};   // 128 accumulator regs

    for (int ty = 0; ty < 3; ty++) {
        const ushort* gA = gA0 + (size_t)(ty * 3) * O_ * C_;
        const ushort* gB = gB0 + (size_t)ty * WP * C_;
        for (int c0 = 0; c0 < C_; c0 += BK) {
            __syncthreads();
            #pragma unroll
            for (int s = 0; s < 6; s++)
                *(uint4*)(&As[Al[s]]) = *(const uint4*)(gA + Ag[s] + c0);
            #pragma unroll
            for (int s = 0; s < 4; s++)
                *(uint4*)(&Bs[Bl[s]]) = *(const uint4*)(gB + Bg[s] + c0);
            if (tid < 32)
                *(uint4*)(&Bs[Bl[4]]) = *(const uint4*)(gB + Bg[4] + c0);
            __syncthreads();

            #pragma unroll
            for (int tx = 0; tx < 3; tx++) {
                #pragma unroll
                for (int ks = 0; ks < 2; ks++) {
                    int ko = ks * 16;
                    bf16x8 af0 = *(const bf16x8*)(&As[tx * 128 * LDK + aO[0] + ko]);
                    bf16x8 af1 = *(const bf16x8*)(&As[tx * 128 * LDK + aO[1] + ko]);
                    bf16x8 bf[4];
                    #pragma unroll
                    for (int jn = 0; jn < 4; jn++)
                        bf[jn] = *(const bf16x8*)(&Bs[bO[tx][jn] + ko]);
                    #pragma unroll
                    for (int jn = 0; jn < 4; jn++)
                        acc[0][jn] = __builtin_amdgcn_mfma_f32_32x32x16_bf16(af0, bf[jn], acc[0][jn], 0, 0, 0);
                    #pragma unroll
                    for (int jn = 0; jn < 4; jn++)
                        acc[1][jn] = __builtin_amdgcn_mfma_f32_32x32x16_bf16(af1, bf[jn], acc[1][jn], 0, 0, 0);
                }
            }
        }
    }

    // --- epilogue: direct stores. C/D: col=lane&31, row=(reg&3)+8*(reg>>2)+4*h
    float* outb = out + ((size_t)b * O_ + (size_t)mt * 128) * (H_ * W_) + (size_t)nt * 256;
    #pragma unroll
    for (int im = 0; im < 2; im++) {
        int obase = wm * 64 + im * 32 + 4 * h;
        #pragma unroll
        for (int jn = 0; jn < 4; jn++) {
            int pcol = wn * 128 + jn * 32 + n31;
            #pragma unroll
            for (int g = 0; g < 4; g++)
                #pragma unroll
                for (int r4 = 0; r4 < 4; r4++)
                    outb[(size_t)(obase + r4 + 8 * g) * (H_ * W_) + pcol] = acc[im][jn][g * 4 + r4];
        }
    }
}

// ---------------------------------------------------------------------------
extern "C" void kernel_launch(void* const* d_in, const int* in_sizes, int n_in,
                              void* d_out, int out_size, void* d_ws, size_t ws_size,
                              hipStream_t stream) {
    const float* x      = (const float*)d_in[0];
    const float* weight = (const float*)d_in[1];
    const float* att_w1 = (const float*)d_in[2];
    const float* att_w2 = (const float*)d_in[3];
    const float* att_b2 = (const float*)d_in[4];
    float* out = (float*)d_out;

    char* ws = (char*)d_ws;
    float* pooled  = (float*)ws;                                  // 16 KiB
    ushort* aggw   = (ushort*)(ws + 32768);                       // 18,874,368 B
    ushort* xp     = (ushort*)(ws + 32768 + 18874368);            // 35,684,352 B

    hipMemsetAsync(pooled, 0, B_ * C_ * sizeof(float), stream);
    pad_pool_kernel<<<B_ * HP, 256, 0, stream>>>(x, xp, pooled);
    att_agg_kernel<<<O_, 256, 0, stream>>>(weight, pooled, att_w1, att_w2, att_b2, aggw);
    conv_kernel<<<512, 256, 0, stream>>>(xp, aggw, out);
}